// Round 13
// baseline (418.585 us; speedup 1.0000x reference)
//
#include <hip/hip_runtime.h>
#include <math.h>

#define BB 2
#define LL 2048
#define SS 2048
#define HH 8
#define EE 64
#define DD 64
#define HE (HH * EE)   // 512
// softmax scale = 1/sqrt(E) = 0.125

// ws layout (384 KB):
//   [0, 128K)     : m32  (B*H*L floats) -- BLAS-grid fp32 M_sp (bit-exact)
//   [128K, 256K)  : rank (B*H*L ints)
//   [256K, 384K)  : maxs (B*H*L floats)

typedef __attribute__((ext_vector_type(8))) short   bf16x8;   // MFMA A/B frag
typedef __attribute__((ext_vector_type(4))) float   f32x4;    // MFMA C/D frag
typedef __attribute__((ext_vector_type(8))) unsigned short u16x8;
typedef __attribute__((ext_vector_type(4))) unsigned short u16x4;

__device__ __forceinline__ unsigned short f2bf(float x) {   // fp32 -> bf16 RNE
    unsigned int u = __float_as_uint(x);
    return (unsigned short)((u + 0x7FFFu + ((u >> 16) & 1u)) >> 16);
}

__device__ __forceinline__ float rdlane(float v, int lane) { // bit-exact copy
    return __uint_as_float(
        (unsigned)__builtin_amdgcn_readlane((int)__float_as_uint(v), lane));
}

// ---------- A: BLAS-grid fp32 M_sp, VMEM + readlane broadcast (R8 exact) --
// Arithmetic sequence IDENTICAL to the verified kernel. DO NOT REORDER.
// R8 = 218us, VGPR 84, proven. R12 showed the 6.9cyc/(rdlane+fmaf) pair is
// readlane THROUGHPUT (~5cyc), not dep stalls -> msp is at its wall:
// uniform-VMEM replicates 512 regs/group (R3 spill), 2q/lane >128 VGPR
// (R9 AGPR churn), LDS broadcast 327us wall (R1), hybrids lose (R10/R11).
__global__ __launch_bounds__(256, 2)
void msp_blas(const float* __restrict__ Q, const float* __restrict__ K,
              float* __restrict__ m32, float* __restrict__ maxs) {
#pragma clang fp contract(off)
    const int bid = blockIdx.x;          // B*H*32 = 512
    const int lt = bid & 31, bh = bid >> 5;
    const int h = bh & 7, b = bh >> 3;
    const int t = threadIdx.x, lq = t & 63, w = t >> 6;
    const int l = lt * 64 + lq;

    float qf[64];
    const float4* qrow = (const float4*)(Q + (((size_t)b * LL + l) * HH + h) * EE);
#pragma unroll
    for (int i = 0; i < 16; i++) {
        float4 v = qrow[i];
        qf[4*i] = v.x; qf[4*i+1] = v.y; qf[4*i+2] = v.z; qf[4*i+3] = v.w;
    }

    const float* Kw = K + (((size_t)b * SS) * HH + h) * EE + (size_t)w * 512 * HE;
    const float* gld = Kw + (size_t)(lq >> 4) * HE + (lq & 15) * 4;

    float4 A0 = *(const float4*)(gld);
    float4 B0 = *(const float4*)(gld + 4 * HE);

    float mx = -1e30f;
    float blk[4];
#pragma unroll 1
    for (int lf = 0; lf < 4; ++lf) {
        float r[8];
#pragma unroll 1
        for (int i8 = 0; i8 < 16; ++i8) {
            const int kc = lf * 128 + i8 * 8;
            const int kn = (kc < 504) ? kc + 8 : 504;

            float4 A1 = *(const float4*)(gld + (size_t)kn * HE);
            float4 B1 = *(const float4*)(gld + (size_t)(kn + 4) * HE);

            float c[8];
#pragma unroll
            for (int j = 0; j < 8; ++j) c[j] = 0.f;
#pragma unroll
            for (int j = 0; j < 4; ++j) {
#pragma unroll
                for (int e4 = 0; e4 < 16; ++e4) {
                    const int ln = j * 16 + e4;
                    c[j] = fmaf(qf[4*e4+0], rdlane(A0.x, ln), c[j]);
                    c[j] = fmaf(qf[4*e4+1], rdlane(A0.y, ln), c[j]);
                    c[j] = fmaf(qf[4*e4+2], rdlane(A0.z, ln), c[j]);
                    c[j] = fmaf(qf[4*e4+3], rdlane(A0.w, ln), c[j]);
                }
            }
#pragma unroll
            for (int j = 0; j < 4; ++j) {
#pragma unroll
                for (int e4 = 0; e4 < 16; ++e4) {
                    const int ln = j * 16 + e4;
                    c[4+j] = fmaf(qf[4*e4+0], rdlane(B0.x, ln), c[4+j]);
                    c[4+j] = fmaf(qf[4*e4+1], rdlane(B0.y, ln), c[4+j]);
                    c[4+j] = fmaf(qf[4*e4+2], rdlane(B0.z, ln), c[4+j]);
                    c[4+j] = fmaf(qf[4*e4+3], rdlane(B0.w, ln), c[4+j]);
                }
            }
#pragma unroll
            for (int j = 0; j < 8; ++j) {
                mx = fmaxf(mx, c[j]);
                if (i8 == 0) r[j] = c[j];
                else         r[j] = __fadd_rn(r[j], c[j]);
            }
            A0 = A1; B0 = B1;
        }
        blk[lf] = __fadd_rn(
            __fadd_rn(__fadd_rn(r[0], r[1]), __fadd_rn(r[2], r[3])),
            __fadd_rn(__fadd_rn(r[4], r[5]), __fadd_rn(r[6], r[7])));
    }
    const float sub = __fadd_rn(__fadd_rn(blk[0], blk[1]),
                                __fadd_rn(blk[2], blk[3]));

    __shared__ float smx[4][64], ssub[4][64];
    smx[w][lq] = mx; ssub[w][lq] = sub;
    __syncthreads();
    if (w == 0) {
        const float m_all = fmaxf(fmaxf(smx[0][lq], smx[1][lq]),
                                  fmaxf(smx[2][lq], smx[3][lq]));
        const float s2048 = __fadd_rn(__fadd_rn(ssub[0][lq], ssub[1][lq]),
                                      __fadd_rn(ssub[2][lq], ssub[3][lq]));
        const float mean = __fmul_rn(s2048, 0.00048828125f);  // /2048 exact
        m32[((size_t)bh << 11) + l]  = __fsub_rn(m_all, mean);
        maxs[((size_t)bh << 11) + l] = m_all;
    }
}

// ---------- B: descending sort, ties -> lower index first (1024 thr) ------
__global__ __launch_bounds__(1024)
void sort_rank(const float* __restrict__ m32, int* __restrict__ rank) {
    __shared__ unsigned int k1[2048];
    __shared__ int pay[2048];
    const int bh = blockIdx.x;
    const int t = threadIdx.x;
    for (int i = t; i < 2048; i += 1024) {
        unsigned int u = __float_as_uint(m32[((size_t)bh << 11) + i]);
        u = (u & 0x80000000u) ? ~u : (u | 0x80000000u);
        k1[i] = u; pay[i] = i;
    }
    __syncthreads();
    for (int k = 2; k <= 2048; k <<= 1) {
        for (int j = k >> 1; j > 0; j >>= 1) {
            for (int i = t; i < 2048; i += 1024) {
                const int ixj = i ^ j;
                if (ixj > i) {
                    unsigned int a1 = k1[i], c1 = k1[ixj];
                    int pa = pay[i], pc = pay[ixj];
                    const bool pre = (a1 > c1) || (a1 == c1 && pa < pc);
                    const bool dir = ((i & k) == 0);
                    if (dir != pre) {
                        k1[i] = c1; k1[ixj] = a1;
                        pay[i] = pc; pay[ixj] = pa;
                    }
                }
            }
            __syncthreads();
        }
    }
    for (int i = t; i < 2048; i += 1024)
        rank[((size_t)bh << 11) + pay[i]] = i;   // inverse permutation
}

// ---------- C: bf16 MFMA flash, 128 q/block, prefetch, XCD-swizzled -------
// Per-query arithmetic IDENTICAL to the verified 4-wave version (each wave
// still runs the same 16-query code over all 32 chunks in the same order).
// Changes are purely structural:
//  * 512 threads / 8 waves -> 128 queries per block: K/V staged once per
//    128 queries (L2/L3 traffic 1GB -> 0.5GB), barriers per query halved.
//  * staging split: threads 0-255 stage K (verbatim old code), threads
//    256-511 stage V-transposed (verbatim old code, tt = t-256).
//  * register prefetch: next chunk's global loads issue BEFORE compute,
//    LDS write after the barrier -> L2/L3 latency hidden under MFMA.
//  * XCD swizzle: bid = (bh&7) + 8*lt + 128*(bh>>3) -> all 16 blocks of a
//    bh round-robin onto one XCD; its 2MB K/V fits the 4MB per-XCD L2.
__global__ __launch_bounds__(512, 1)
void flash_mfma(const float* __restrict__ Q, const float* __restrict__ K,
                const float* __restrict__ V, const float* __restrict__ maxs,
                const int* __restrict__ rank, float* __restrict__ out) {
    __shared__ unsigned short ldsK[64 * 72];        // 9216 B
    __shared__ unsigned short ldsVT[64 * 72];       // 9216 B  (V transposed)
    __shared__ unsigned short ldsP[8 * 16 * 72];    // 18432 B (per-wave P)

    const int bid = blockIdx.x;          // 256, XCD-swizzled
    const int bh = (bid & 7) | (((bid >> 7) & 1) << 3);
    const int lt = (bid >> 3) & 15;      // 16 tiles of 128 queries
    const int h = bh & 7, b = bh >> 3;
    const int t = threadIdx.x, lane = t & 63, w = t >> 6;   // w = 0..7
    const int quad = lane >> 4, cl = lane & 15;

    const size_t kvbase = (((size_t)b * SS) * HH + h) * EE;

    // Q A-frags: A[m=cl][k=quad*8+j (+32*ef)]
    bf16x8 qa[2];
    {
        const float* qp = Q + (((size_t)b * LL + (lt * 128 + w * 16 + cl)) * HH + h) * EE
                          + quad * 8;
#pragma unroll
        for (int ef = 0; ef < 2; ++ef) {
            float4 a0 = *(const float4*)(qp + ef * 32);
            float4 a1 = *(const float4*)(qp + ef * 32 + 4);
            short* s = (short*)&qa[ef];
            s[0] = (short)f2bf(a0.x); s[1] = (short)f2bf(a0.y);
            s[2] = (short)f2bf(a0.z); s[3] = (short)f2bf(a0.w);
            s[4] = (short)f2bf(a1.x); s[5] = (short)f2bf(a1.y);
            s[6] = (short)f2bf(a1.z); s[7] = (short)f2bf(a1.w);
        }
    }

    // per-lane row constants (rows quad*4+reg)
    float negpm[4];
    int rk[4];
#pragma unroll
    for (int reg = 0; reg < 4; ++reg) {
        const int qg = lt * 128 + w * 16 + quad * 4 + reg;
        negpm[reg] = -0.125f * maxs[((size_t)bh << 11) + qg];
        rk[reg]    = rank[((size_t)bh << 11) + qg];
    }

    f32x4 accO[4];
#pragma unroll
    for (int nt = 0; nt < 4; ++nt) accO[nt] = (f32x4){0.f, 0.f, 0.f, 0.f};
    float ell[4] = {0.f, 0.f, 0.f, 0.f};

    const int pbase = w * (16 * 72);

    // staging roles: t<256 -> K rows; t>=256 -> V transposed (tt = t-256)
    const int st = t & 255;
    float4 f0, f1, f2, f3;

    // prologue: load + write chunk 0
    {
        if (t < 256) {
            const float* gp = K + kvbase + (size_t)(st >> 2) * HE + (st & 3) * 16;
            f0 = ((const float4*)gp)[0]; f1 = ((const float4*)gp)[1];
            f2 = ((const float4*)gp)[2]; f3 = ((const float4*)gp)[3];
        } else {
            const float* gv = V + kvbase + (size_t)((st & 15) * 4) * HE + (st >> 4) * 4;
            f0 = *(const float4*)(gv);
            f1 = *(const float4*)(gv + HE);
            f2 = *(const float4*)(gv + 2 * HE);
            f3 = *(const float4*)(gv + 3 * HE);
        }
        if (t < 256) {
            const int row = st >> 2, col0 = (st & 3) * 16;
            u16x8 w0 = { f2bf(f0.x), f2bf(f0.y), f2bf(f0.z), f2bf(f0.w),
                         f2bf(f1.x), f2bf(f1.y), f2bf(f1.z), f2bf(f1.w) };
            u16x8 w1 = { f2bf(f2.x), f2bf(f2.y), f2bf(f2.z), f2bf(f2.w),
                         f2bf(f3.x), f2bf(f3.y), f2bf(f3.z), f2bf(f3.w) };
            *(u16x8*)&ldsK[row * 72 + col0]     = w0;
            *(u16x8*)&ldsK[row * 72 + col0 + 8] = w1;
        } else {
            const int s0 = (st & 15) * 4, d0 = (st >> 4) * 4;
            u16x4 p0 = { f2bf(f0.x), f2bf(f1.x), f2bf(f2.x), f2bf(f3.x) };
            u16x4 p1 = { f2bf(f0.y), f2bf(f1.y), f2bf(f2.y), f2bf(f3.y) };
            u16x4 p2 = { f2bf(f0.z), f2bf(f1.z), f2bf(f2.z), f2bf(f3.z) };
            u16x4 p3 = { f2bf(f0.w), f2bf(f1.w), f2bf(f2.w), f2bf(f3.w) };
            *(u16x4*)&ldsVT[(d0 + 0) * 72 + s0] = p0;
            *(u16x4*)&ldsVT[(d0 + 1) * 72 + s0] = p1;
            *(u16x4*)&ldsVT[(d0 + 2) * 72 + s0] = p2;
            *(u16x4*)&ldsVT[(d0 + 3) * 72 + s0] = p3;
        }
    }
    __syncthreads();

#pragma unroll 1
    for (int c0 = 0; c0 < SS; c0 += 64) {
        const bool more = (c0 + 64 < SS);
        // ---- prefetch next chunk into registers (latency hides under MFMA)
        if (more) {
            if (t < 256) {
                const float* gp = K + kvbase
                    + (size_t)(c0 + 64 + (st >> 2)) * HE + (st & 3) * 16;
                f0 = ((const float4*)gp)[0]; f1 = ((const float4*)gp)[1];
                f2 = ((const float4*)gp)[2]; f3 = ((const float4*)gp)[3];
            } else {
                const float* gv = V + kvbase
                    + (size_t)(c0 + 64 + (st & 15) * 4) * HE + (st >> 4) * 4;
                f0 = *(const float4*)(gv);
                f1 = *(const float4*)(gv + HE);
                f2 = *(const float4*)(gv + 2 * HE);
                f3 = *(const float4*)(gv + 3 * HE);
            }
        }

        // ---- QK^T: S[m=q16][n=s64] = A(Q) x B(K), B[k=e][n=s]=K[s][e] ----
        f32x4 Sc[4];
#pragma unroll
        for (int nt = 0; nt < 4; ++nt) {
            bf16x8 bk0 = *(const bf16x8*)&ldsK[(nt * 16 + cl) * 72 + quad * 8];
            bf16x8 bk1 = *(const bf16x8*)&ldsK[(nt * 16 + cl) * 72 + quad * 8 + 32];
            f32x4 z = (f32x4){0.f, 0.f, 0.f, 0.f};
            z = __builtin_amdgcn_mfma_f32_16x16x32_bf16(qa[0], bk0, z, 0, 0, 0);
            z = __builtin_amdgcn_mfma_f32_16x16x32_bf16(qa[1], bk1, z, 0, 0, 0);
            Sc[nt] = z;
        }

        // ---- softmax numerator + P (bf16) into A-layout LDS ----
#pragma unroll
        for (int nt = 0; nt < 4; ++nt) {
#pragma unroll
            for (int reg = 0; reg < 4; ++reg) {
                const float p = __expf(fmaf(Sc[nt][reg], 0.125f, negpm[reg]));
                ell[reg] += p;
                ldsP[pbase + (quad * 4 + reg) * 72 + nt * 16 + cl] = f2bf(p);
            }
        }

        // ---- PV: O[m=q16][n=d64] += A(P) x B(V), B[k=s][n=d]=VT[d][s] ----
        bf16x8 pa0 = *(const bf16x8*)&ldsP[pbase + cl * 72 + quad * 8];
        bf16x8 pa1 = *(const bf16x8*)&ldsP[pbase + cl * 72 + quad * 8 + 32];
#pragma unroll
        for (int nt = 0; nt < 4; ++nt) {
            bf16x8 bv0 = *(const bf16x8*)&ldsVT[(nt * 16 + cl) * 72 + quad * 8];
            bf16x8 bv1 = *(const bf16x8*)&ldsVT[(nt * 16 + cl) * 72 + quad * 8 + 32];
            accO[nt] = __builtin_amdgcn_mfma_f32_16x16x32_bf16(pa0, bv0, accO[nt], 0, 0, 0);
            accO[nt] = __builtin_amdgcn_mfma_f32_16x16x32_bf16(pa1, bv1, accO[nt], 0, 0, 0);
        }

        __syncthreads();      // all waves done reading this chunk's LDS
        if (more) {           // write prefetched chunk (uniform branch)
            if (t < 256) {
                const int row = st >> 2, col0 = (st & 3) * 16;
                u16x8 w0 = { f2bf(f0.x), f2bf(f0.y), f2bf(f0.z), f2bf(f0.w),
                             f2bf(f1.x), f2bf(f1.y), f2bf(f1.z), f2bf(f1.w) };
                u16x8 w1 = { f2bf(f2.x), f2bf(f2.y), f2bf(f2.z), f2bf(f2.w),
                             f2bf(f3.x), f2bf(f3.y), f2bf(f3.z), f2bf(f3.w) };
                *(u16x8*)&ldsK[row * 72 + col0]     = w0;
                *(u16x8*)&ldsK[row * 72 + col0 + 8] = w1;
            } else {
                const int s0 = (st & 15) * 4, d0 = (st >> 4) * 4;
                u16x4 p0 = { f2bf(f0.x), f2bf(f1.x), f2bf(f2.x), f2bf(f3.x) };
                u16x4 p1 = { f2bf(f0.y), f2bf(f1.y), f2bf(f2.y), f2bf(f3.y) };
                u16x4 p2 = { f2bf(f0.z), f2bf(f1.z), f2bf(f2.z), f2bf(f3.z) };
                u16x4 p3 = { f2bf(f0.w), f2bf(f1.w), f2bf(f2.w), f2bf(f3.w) };
                *(u16x4*)&ldsVT[(d0 + 0) * 72 + s0] = p0;
                *(u16x4*)&ldsVT[(d0 + 1) * 72 + s0] = p1;
                *(u16x4*)&ldsVT[(d0 + 2) * 72 + s0] = p2;
                *(u16x4*)&ldsVT[(d0 + 3) * 72 + s0] = p3;
            }
        }
        __syncthreads();
    }

    // ---- ell: reduce across the 16 lanes sharing each row (within quad) ----
#pragma unroll
    for (int reg = 0; reg < 4; ++reg) {
        float e = ell[reg];
        e += __shfl_xor(e, 1);
        e += __shfl_xor(e, 2);
        e += __shfl_xor(e, 4);
        e += __shfl_xor(e, 8);
        ell[reg] = 1.0f / e;
    }

    // ---- scatter O rows by rank ----
#pragma unroll
    for (int reg = 0; reg < 4; ++reg) {
        float* orow = out + (((size_t)b * LL + rk[reg]) * HH + h) * DD;
#pragma unroll
        for (int nt = 0; nt < 4; ++nt)
            orow[nt * 16 + cl] = accO[nt][reg] * ell[reg];
    }
}

extern "C" void kernel_launch(void* const* d_in, const int* in_sizes, int n_in,
                              void* d_out, int out_size, void* d_ws, size_t ws_size,
                              hipStream_t stream) {
    const float* Q = (const float*)d_in[0];
    const float* K = (const float*)d_in[1];
    const float* V = (const float*)d_in[2];
    float* out = (float*)d_out;

    float* m32  = (float*)d_ws;                          // 128 KB
    int*   rank = (int*)((char*)d_ws + 131072);          // 128 KB
    float* maxs = (float*)((char*)d_ws + 262144);        // 128 KB

    msp_blas<<<BB * HH * (LL / 64), 256, 0, stream>>>(Q, K, m32, maxs);
    sort_rank<<<BB * HH, 1024, 0, stream>>>(m32, rank);
    flash_mfma<<<BB * HH * (LL / 128), 512, 0, stream>>>(Q, K, V, maxs, rank, out);
}

// Round 14
// 400.878 us; speedup vs baseline: 1.0442x; 1.0442x over previous
//
#include <hip/hip_runtime.h>
#include <math.h>

#define BB 2
#define LL 2048
#define SS 2048
#define HH 8
#define EE 64
#define DD 64
#define HE (HH * EE)   // 512
// softmax scale = 1/sqrt(E) = 0.125

// ws layout (384 KB):
//   [0, 128K)     : m32  (B*H*L floats) -- BLAS-grid fp32 M_sp (bit-exact)
//   [128K, 256K)  : rank (B*H*L ints)
//   [256K, 384K)  : maxs (B*H*L floats)

typedef __attribute__((ext_vector_type(8))) short   bf16x8;   // MFMA A/B frag
typedef __attribute__((ext_vector_type(4))) float   f32x4;    // MFMA C/D frag
typedef __attribute__((ext_vector_type(8))) unsigned short u16x8;
typedef __attribute__((ext_vector_type(4))) unsigned short u16x4;

__device__ __forceinline__ unsigned short f2bf(float x) {   // fp32 -> bf16 RNE
    unsigned int u = __float_as_uint(x);
    return (unsigned short)((u + 0x7FFFu + ((u >> 16) & 1u)) >> 16);
}

__device__ __forceinline__ float rdlane(float v, int lane) { // bit-exact copy
    return __uint_as_float(
        (unsigned)__builtin_amdgcn_readlane((int)__float_as_uint(v), lane));
}

// ---------- A: BLAS-grid fp32 M_sp, VMEM + readlane broadcast (R8 exact) --
// Arithmetic sequence IDENTICAL to the verified kernel. DO NOT REORDER.
// R8 = 218us, VGPR 84, proven at ~93% of the readlane-throughput wall
// (~5cyc/readlane). All alternatives explored and dead: uniform-VMEM
// (R3 spill), 2q/lane (R9 >128 VGPR AGPR churn), LDS broadcast (R1 327us
// pipe wall), hybrids (R10/R11 lose to pure readlane). msp is DONE.
__global__ __launch_bounds__(256, 2)
void msp_blas(const float* __restrict__ Q, const float* __restrict__ K,
              float* __restrict__ m32, float* __restrict__ maxs) {
#pragma clang fp contract(off)
    const int bid = blockIdx.x;          // B*H*32 = 512
    const int lt = bid & 31, bh = bid >> 5;
    const int h = bh & 7, b = bh >> 3;
    const int t = threadIdx.x, lq = t & 63, w = t >> 6;
    const int l = lt * 64 + lq;

    float qf[64];
    const float4* qrow = (const float4*)(Q + (((size_t)b * LL + l) * HH + h) * EE);
#pragma unroll
    for (int i = 0; i < 16; i++) {
        float4 v = qrow[i];
        qf[4*i] = v.x; qf[4*i+1] = v.y; qf[4*i+2] = v.z; qf[4*i+3] = v.w;
    }

    const float* Kw = K + (((size_t)b * SS) * HH + h) * EE + (size_t)w * 512 * HE;
    const float* gld = Kw + (size_t)(lq >> 4) * HE + (lq & 15) * 4;

    float4 A0 = *(const float4*)(gld);
    float4 B0 = *(const float4*)(gld + 4 * HE);

    float mx = -1e30f;
    float blk[4];
#pragma unroll 1
    for (int lf = 0; lf < 4; ++lf) {
        float r[8];
#pragma unroll 1
        for (int i8 = 0; i8 < 16; ++i8) {
            const int kc = lf * 128 + i8 * 8;
            const int kn = (kc < 504) ? kc + 8 : 504;

            float4 A1 = *(const float4*)(gld + (size_t)kn * HE);
            float4 B1 = *(const float4*)(gld + (size_t)(kn + 4) * HE);

            float c[8];
#pragma unroll
            for (int j = 0; j < 8; ++j) c[j] = 0.f;
#pragma unroll
            for (int j = 0; j < 4; ++j) {
#pragma unroll
                for (int e4 = 0; e4 < 16; ++e4) {
                    const int ln = j * 16 + e4;
                    c[j] = fmaf(qf[4*e4+0], rdlane(A0.x, ln), c[j]);
                    c[j] = fmaf(qf[4*e4+1], rdlane(A0.y, ln), c[j]);
                    c[j] = fmaf(qf[4*e4+2], rdlane(A0.z, ln), c[j]);
                    c[j] = fmaf(qf[4*e4+3], rdlane(A0.w, ln), c[j]);
                }
            }
#pragma unroll
            for (int j = 0; j < 4; ++j) {
#pragma unroll
                for (int e4 = 0; e4 < 16; ++e4) {
                    const int ln = j * 16 + e4;
                    c[4+j] = fmaf(qf[4*e4+0], rdlane(B0.x, ln), c[4+j]);
                    c[4+j] = fmaf(qf[4*e4+1], rdlane(B0.y, ln), c[4+j]);
                    c[4+j] = fmaf(qf[4*e4+2], rdlane(B0.z, ln), c[4+j]);
                    c[4+j] = fmaf(qf[4*e4+3], rdlane(B0.w, ln), c[4+j]);
                }
            }
#pragma unroll
            for (int j = 0; j < 8; ++j) {
                mx = fmaxf(mx, c[j]);
                if (i8 == 0) r[j] = c[j];
                else         r[j] = __fadd_rn(r[j], c[j]);
            }
            A0 = A1; B0 = B1;
        }
        blk[lf] = __fadd_rn(
            __fadd_rn(__fadd_rn(r[0], r[1]), __fadd_rn(r[2], r[3])),
            __fadd_rn(__fadd_rn(r[4], r[5]), __fadd_rn(r[6], r[7])));
    }
    const float sub = __fadd_rn(__fadd_rn(blk[0], blk[1]),
                                __fadd_rn(blk[2], blk[3]));

    __shared__ float smx[4][64], ssub[4][64];
    smx[w][lq] = mx; ssub[w][lq] = sub;
    __syncthreads();
    if (w == 0) {
        const float m_all = fmaxf(fmaxf(smx[0][lq], smx[1][lq]),
                                  fmaxf(smx[2][lq], smx[3][lq]));
        const float s2048 = __fadd_rn(__fadd_rn(ssub[0][lq], ssub[1][lq]),
                                      __fadd_rn(ssub[2][lq], ssub[3][lq]));
        const float mean = __fmul_rn(s2048, 0.00048828125f);  // /2048 exact
        m32[((size_t)bh << 11) + l]  = __fsub_rn(m_all, mean);
        maxs[((size_t)bh << 11) + l] = m_all;
    }
}

// ---------- B: descending sort, ties -> lower index first (R8 exact) ------
__global__ __launch_bounds__(256)
void sort_rank(const float* __restrict__ m32, int* __restrict__ rank) {
    __shared__ unsigned int k1[2048];
    __shared__ int pay[2048];
    const int bh = blockIdx.x;
    const int t = threadIdx.x;
    for (int i = t; i < 2048; i += 256) {
        unsigned int u = __float_as_uint(m32[((size_t)bh << 11) + i]);
        u = (u & 0x80000000u) ? ~u : (u | 0x80000000u);
        k1[i] = u; pay[i] = i;
    }
    __syncthreads();
    for (int k = 2; k <= 2048; k <<= 1) {
        for (int j = k >> 1; j > 0; j >>= 1) {
            for (int i = t; i < 2048; i += 256) {
                const int ixj = i ^ j;
                if (ixj > i) {
                    unsigned int a1 = k1[i], c1 = k1[ixj];
                    int pa = pay[i], pc = pay[ixj];
                    const bool pre = (a1 > c1) || (a1 == c1 && pa < pc);
                    const bool dir = ((i & k) == 0);
                    if (dir != pre) {
                        k1[i] = c1; k1[ixj] = a1;
                        pay[i] = pc; pay[ixj] = pa;
                    }
                }
            }
            __syncthreads();
        }
    }
    for (int i = t; i < 2048; i += 256)
        rank[((size_t)bh << 11) + pay[i]] = i;   // inverse permutation
}

// ---------- C: bf16 MFMA flash (R8 structure) + XCD-locality swizzle ------
// Wave w owns 16 queries (rows lt*64 + w*16 .. +15) over the FULL S range.
// Per 64-s chunk: QK via mfma_16x16x32_bf16 (8), exp, P->LDS (A-layout),
// PV via mfma (8). K staged [s][e], V staged transposed [d][s], pitch 72.
// R13 lesson: 512-thread/1-block-per-CU serializes at the per-chunk
// barriers (no co-resident block) -> keep 256 threads, 2 blocks/CU.
// NEW (only change vs R8): grid decomposition bh = bid&15, lt = bid>>4.
// bid%8 == bh%8, so under round-robin workgroup->XCD dispatch all 32
// blocks of a bh land on ONE XCD and march through K/V chunks in near
// lockstep -> instantaneous working set ~2 chunks (256 KB) resident in
// the 4 MB per-XCD L2; K/V re-reads become L2 hits instead of L3.
// Pure locality change: arithmetic and output byte-identical.
__global__ __launch_bounds__(256, 2)
void flash_mfma(const float* __restrict__ Q, const float* __restrict__ K,
                const float* __restrict__ V, const float* __restrict__ maxs,
                const int* __restrict__ rank, float* __restrict__ out) {
    __shared__ unsigned short ldsK[64 * 72];        // 9216 B
    __shared__ unsigned short ldsVT[64 * 72];       // 9216 B  (V transposed)
    __shared__ unsigned short ldsP[4 * 16 * 72];    // 9216 B  (per-wave P)

    const int bid = blockIdx.x;          // 512, XCD-locality decomposition
    const int bh = bid & 15, lt = bid >> 4;
    const int h = bh & 7, b = bh >> 3;
    const int t = threadIdx.x, lane = t & 63, w = t >> 6;
    const int quad = lane >> 4, cl = lane & 15;

    const size_t kvbase = (((size_t)b * SS) * HH + h) * EE;

    // Q A-frags: A[m=cl][k=quad*8+j (+32*ef)]
    bf16x8 qa[2];
    {
        const float* qp = Q + (((size_t)b * LL + (lt * 64 + w * 16 + cl)) * HH + h) * EE
                          + quad * 8;
#pragma unroll
        for (int ef = 0; ef < 2; ++ef) {
            float4 a0 = *(const float4*)(qp + ef * 32);
            float4 a1 = *(const float4*)(qp + ef * 32 + 4);
            short* s = (short*)&qa[ef];
            s[0] = (short)f2bf(a0.x); s[1] = (short)f2bf(a0.y);
            s[2] = (short)f2bf(a0.z); s[3] = (short)f2bf(a0.w);
            s[4] = (short)f2bf(a1.x); s[5] = (short)f2bf(a1.y);
            s[6] = (short)f2bf(a1.z); s[7] = (short)f2bf(a1.w);
        }
    }

    // per-lane row constants (rows quad*4+reg)
    float negpm[4];
    int rk[4];
#pragma unroll
    for (int reg = 0; reg < 4; ++reg) {
        const int qg = lt * 64 + w * 16 + quad * 4 + reg;
        negpm[reg] = -0.125f * maxs[((size_t)bh << 11) + qg];
        rk[reg]    = rank[((size_t)bh << 11) + qg];
    }

    f32x4 accO[4];
#pragma unroll
    for (int nt = 0; nt < 4; ++nt) accO[nt] = (f32x4){0.f, 0.f, 0.f, 0.f};
    float ell[4] = {0.f, 0.f, 0.f, 0.f};

    const int pbase = w * (16 * 72);

#pragma unroll 1
    for (int c0 = 0; c0 < SS; c0 += 64) {
        __syncthreads();
        // ---- stage K[s][e] -> bf16, row-major pitch 72 ----
        {
            const int row = t >> 2, col0 = (t & 3) * 16;
            const float* gp = K + kvbase + (size_t)(c0 + row) * HE + col0;
            float4 f0 = ((const float4*)gp)[0];
            float4 f1 = ((const float4*)gp)[1];
            float4 f2 = ((const float4*)gp)[2];
            float4 f3 = ((const float4*)gp)[3];
            u16x8 w0 = { f2bf(f0.x), f2bf(f0.y), f2bf(f0.z), f2bf(f0.w),
                         f2bf(f1.x), f2bf(f1.y), f2bf(f1.z), f2bf(f1.w) };
            u16x8 w1 = { f2bf(f2.x), f2bf(f2.y), f2bf(f2.z), f2bf(f2.w),
                         f2bf(f3.x), f2bf(f3.y), f2bf(f3.z), f2bf(f3.w) };
            *(u16x8*)&ldsK[row * 72 + col0]     = w0;
            *(u16x8*)&ldsK[row * 72 + col0 + 8] = w1;
        }
        // ---- stage V transposed: VT[d][s] bf16, pitch 72 ----
        {
            const int s0 = (t & 15) * 4, d0 = (t >> 4) * 4;
            const float* gv = V + kvbase + (size_t)(c0 + s0) * HE + d0;
            float4 v0 = *(const float4*)(gv);
            float4 v1 = *(const float4*)(gv + HE);
            float4 v2 = *(const float4*)(gv + 2 * HE);
            float4 v3 = *(const float4*)(gv + 3 * HE);
            u16x4 p0 = { f2bf(v0.x), f2bf(v1.x), f2bf(v2.x), f2bf(v3.x) };
            u16x4 p1 = { f2bf(v0.y), f2bf(v1.y), f2bf(v2.y), f2bf(v3.y) };
            u16x4 p2 = { f2bf(v0.z), f2bf(v1.z), f2bf(v2.z), f2bf(v3.z) };
            u16x4 p3 = { f2bf(v0.w), f2bf(v1.w), f2bf(v2.w), f2bf(v3.w) };
            *(u16x4*)&ldsVT[(d0 + 0) * 72 + s0] = p0;
            *(u16x4*)&ldsVT[(d0 + 1) * 72 + s0] = p1;
            *(u16x4*)&ldsVT[(d0 + 2) * 72 + s0] = p2;
            *(u16x4*)&ldsVT[(d0 + 3) * 72 + s0] = p3;
        }
        __syncthreads();

        // ---- QK^T: S[m=q16][n=s64] = A(Q) x B(K), B[k=e][n=s]=K[s][e] ----
        f32x4 Sc[4];
#pragma unroll
        for (int nt = 0; nt < 4; ++nt) {
            bf16x8 bk0 = *(const bf16x8*)&ldsK[(nt * 16 + cl) * 72 + quad * 8];
            bf16x8 bk1 = *(const bf16x8*)&ldsK[(nt * 16 + cl) * 72 + quad * 8 + 32];
            f32x4 z = (f32x4){0.f, 0.f, 0.f, 0.f};
            z = __builtin_amdgcn_mfma_f32_16x16x32_bf16(qa[0], bk0, z, 0, 0, 0);
            z = __builtin_amdgcn_mfma_f32_16x16x32_bf16(qa[1], bk1, z, 0, 0, 0);
            Sc[nt] = z;
        }

        // ---- softmax numerator + P (bf16) into A-layout LDS ----
#pragma unroll
        for (int nt = 0; nt < 4; ++nt) {
#pragma unroll
            for (int reg = 0; reg < 4; ++reg) {
                const float p = __expf(fmaf(Sc[nt][reg], 0.125f, negpm[reg]));
                ell[reg] += p;
                ldsP[pbase + (quad * 4 + reg) * 72 + nt * 16 + cl] = f2bf(p);
            }
        }

        // ---- PV: O[m=q16][n=d64] += A(P) x B(V), B[k=s][n=d]=VT[d][s] ----
        bf16x8 pa0 = *(const bf16x8*)&ldsP[pbase + cl * 72 + quad * 8];
        bf16x8 pa1 = *(const bf16x8*)&ldsP[pbase + cl * 72 + quad * 8 + 32];
#pragma unroll
        for (int nt = 0; nt < 4; ++nt) {
            bf16x8 bv0 = *(const bf16x8*)&ldsVT[(nt * 16 + cl) * 72 + quad * 8];
            bf16x8 bv1 = *(const bf16x8*)&ldsVT[(nt * 16 + cl) * 72 + quad * 8 + 32];
            accO[nt] = __builtin_amdgcn_mfma_f32_16x16x32_bf16(pa0, bv0, accO[nt], 0, 0, 0);
            accO[nt] = __builtin_amdgcn_mfma_f32_16x16x32_bf16(pa1, bv1, accO[nt], 0, 0, 0);
        }
    }

    // ---- ell: reduce across the 16 lanes sharing each row (within quad) ----
#pragma unroll
    for (int reg = 0; reg < 4; ++reg) {
        float e = ell[reg];
        e += __shfl_xor(e, 1);
        e += __shfl_xor(e, 2);
        e += __shfl_xor(e, 4);
        e += __shfl_xor(e, 8);
        ell[reg] = 1.0f / e;
    }

    // ---- scatter O rows by rank ----
#pragma unroll
    for (int reg = 0; reg < 4; ++reg) {
        float* orow = out + (((size_t)b * LL + rk[reg]) * HH + h) * DD;
#pragma unroll
        for (int nt = 0; nt < 4; ++nt)
            orow[nt * 16 + cl] = accO[nt][reg] * ell[reg];
    }
}

extern "C" void kernel_launch(void* const* d_in, const int* in_sizes, int n_in,
                              void* d_out, int out_size, void* d_ws, size_t ws_size,
                              hipStream_t stream) {
    const float* Q = (const float*)d_in[0];
    const float* K = (const float*)d_in[1];
    const float* V = (const float*)d_in[2];
    float* out = (float*)d_out;

    float* m32  = (float*)d_ws;                          // 128 KB
    int*   rank = (int*)((char*)d_ws + 131072);          // 128 KB
    float* maxs = (float*)((char*)d_ws + 262144);        // 128 KB

    msp_blas<<<BB * HH * (LL / 64), 256, 0, stream>>>(Q, K, m32, maxs);
    sort_rank<<<BB * HH, 256, 0, stream>>>(m32, rank);
    flash_mfma<<<BB * HH * (LL / 64), 256, 0, stream>>>(Q, K, V, maxs, rank, out);
}